// Round 10
// baseline (11610.473 us; speedup 1.0000x reference)
//
#include <hip/hip_runtime.h>
#include <hip/hip_fp16.h>

constexpr int kB = 128;
constexpr int kN = 1000;
constexpr int kE = 128;
constexpr int kH = 8;
constexpr float kFP8Scale = 64.f;         // fp8 values stored as v*64
constexpr float kQKScale = 0.25f / 64.f;  // 1/sqrt(16) folded with 1/64

typedef _Float16 h2 __attribute__((ext_vector_type(2)));
typedef float f2 __attribute__((ext_vector_type(2)));

__device__ __forceinline__ h2 pkrtz(float a, float b) {
  return __builtin_bit_cast(h2, __builtin_amdgcn_cvt_pkrtz(a, b));
}

__device__ __forceinline__ float fast_tanh(float x) {
  float t = __expf(2.f * x);
  return 1.f - 2.f / (t + 1.f);
}

__device__ __forceinline__ unsigned char enc_fp8(float v) {
  unsigned p = __builtin_amdgcn_cvt_pk_fp8_f32(v, v, 0, false);
  return (unsigned char)(p & 0xFF);
}

// packed fp8-pair dot: sacc += {fp8lo pair}*qa + {fp8hi pair}*qb  (v_pk_fma)
__device__ __forceinline__ void dotp(unsigned u, f2 qa, f2 qb, f2& sacc) {
  f2 lo = __builtin_amdgcn_cvt_pk_f32_fp8(u, false);
  f2 hi = __builtin_amdgcn_cvt_pk_f32_fp8(u, true);
  sacc += lo * qa;
  sacc += hi * qb;
}
// 16-elem fp8 dot (one uint4) against 16 f32 elems in q2[0..7] (f2 pairs).
__device__ __forceinline__ float dot16p(uint4 tq, const f2* q2) {
  f2 s = {0.f, 0.f};
  dotp(tq.x, q2[0], q2[1], s);
  dotp(tq.y, q2[2], q2[3], s);
  dotp(tq.z, q2[4], q2[5], s);
  dotp(tq.w, q2[6], q2[7], s);
  return s.x + s.y;
}
// packed V accumulate: a0 += hv2*{lo pair}; a1 += hv2*{hi pair}
__device__ __forceinline__ void vaccp(unsigned u, f2 hv2, f2& a0, f2& a1) {
  f2 lo = __builtin_amdgcn_cvt_pk_f32_fp8(u, false);
  f2 hi = __builtin_amdgcn_cvt_pk_f32_fp8(u, true);
  a0 += hv2 * lo;
  a1 += hv2 * hi;
}
// unpack 16 f16 (two uint4) -> 8 f2 of f32
__device__ __forceinline__ void unpack16(uint4 a, uint4 b, f2* q2) {
  unsigned w[8] = {a.x, a.y, a.z, a.w, b.x, b.y, b.z, b.w};
#pragma unroll
  for (int i = 0; i < 8; ++i) {
    h2 hh = __builtin_bit_cast(h2, w[i]);
    q2[i] = f2{(float)hh.x, (float)hh.y};
  }
}
// unpack one packed f16 pair -> f2
__device__ __forceinline__ f2 up2(unsigned u) {
  h2 hh = __builtin_bit_cast(h2, u);
  return f2{(float)hh.x, (float)hh.y};
}

// max+argmax combine; tie -> smaller node id (jnp.argmax semantics).
__device__ __forceinline__ void maxcomb(float& m, int& a, float mo, int ao) {
  bool take = (mo > m) || (mo == m && ao < a);
  m = take ? mo : m;
  a = take ? ao : a;
}

// ---- DPP cross-lane helpers (VALU pipe, not DS) ---------------------------
// 0xB1 = quad_perm xor1, 0x4E = quad_perm xor2, 0x141 = row_half_mirror
// (xor4-equiv within octet), 0x128 = row_ror:8 (xor8-equiv within 16 lanes).
template <int CTRL>
__device__ __forceinline__ float dpp_bcastf(float x) {
  return __builtin_bit_cast(
      float, __builtin_amdgcn_update_dpp(0, __builtin_bit_cast(int, x), CTRL,
                                         0xf, 0xf, true));
}
template <int CTRL>
__device__ __forceinline__ int dpp_bcasti(int x) {
  return __builtin_amdgcn_update_dpp(0, x, CTRL, 0xf, 0xf, true);
}
template <int CTRL>
__device__ __forceinline__ float dpp_addf(float x) {
  return x + dpp_bcastf<CTRL>(x);
}
template <int CTRL>
__device__ __forceinline__ void dpp_maxcomb(float& m, int& a) {
  float mo = dpp_bcastf<CTRL>(m);
  int ao = dpp_bcasti<CTRL>(a);
  maxcomb(m, a, mo, ao);
}

// LDS-only barrier: drains DS ops, leaves global register-loads in flight.
__device__ __forceinline__ void barrier_lds() {
  asm volatile("s_waitcnt lgkmcnt(0)" ::: "memory");
  __builtin_amdgcn_s_barrier();
  asm volatile("" ::: "memory");
}

// ---------------------------------------------------------------------------
// Kernel A: qkv projection -> fp8 (value*64) k / v / logit_k.
// ---------------------------------------------------------------------------
__global__ __launch_bounds__(384) void qkv_kernel(
    const float* __restrict__ ne, const float* __restrict__ Wqkv,
    const float* __restrict__ bqkv, unsigned char* __restrict__ kq,
    unsigned char* __restrict__ vq, unsigned char* __restrict__ lkq) {
  __shared__ float rows[16 * kE];
  int b = blockIdx.x;
  int n0 = blockIdx.y * 16;
  int ntile = min(16, kN - n0);
  int tid = threadIdx.x;

  for (int idx = tid; idx < ntile * kE; idx += 384)
    rows[idx] = ne[(b * kN + n0) * kE + idx];
  __syncthreads();

  int j = tid;  // 0..383
  float acc[16];
#pragma unroll
  for (int r = 0; r < 16; ++r) acc[r] = 0.f;
  for (int i = 0; i < kE; ++i) {
    float w = Wqkv[i * (3 * kE) + j];
#pragma unroll
    for (int r = 0; r < 16; ++r) acc[r] += rows[r * kE + i] * w;
  }
  float bias = bqkv[j];
  unsigned char* dst;
  int col;
  if (j < kE) { dst = kq; col = j; }
  else if (j < 2 * kE) { dst = vq; col = j - kE; }
  else { dst = lkq; col = j - 2 * kE; }
  for (int r = 0; r < ntile; ++r)
    dst[(size_t)(b * kN + n0 + r) * kE + col] =
        enc_fp8((acc[r] + bias) * kFP8Scale);
}

// ---------------------------------------------------------------------------
// Kernel B: qbase[b] = ge@Wfix + bfix + first@Wstep_top + bstep  (fp32)
// ---------------------------------------------------------------------------
__global__ __launch_bounds__(128) void qbase_kernel(
    const float* __restrict__ ne, const float* __restrict__ ge,
    const float* __restrict__ Wfix, const float* __restrict__ bfix,
    const float* __restrict__ Wstep, const float* __restrict__ bstep,
    float* __restrict__ qbase) {
  __shared__ float g[kE], f[kE];
  int b = blockIdx.x, e = threadIdx.x;
  g[e] = ge[b * kE + e];
  f[e] = ne[(size_t)b * kN * kE + e];  // node 0
  __syncthreads();
  float acc = bfix[e] + bstep[e];
  for (int i = 0; i < kE; ++i)
    acc += g[i] * Wfix[i * kE + e] + f[i] * Wstep[i * kE + e];
  qbase[b * kE + e] = acc;
}

// ---------------------------------------------------------------------------
// Kernel B2: qstep[b,n] = (qbase[b] + ne[b,n] @ Wbot) * kQKScale, f16.
// ---------------------------------------------------------------------------
__global__ __launch_bounds__(128) void qstep_kernel(
    const float* __restrict__ ne, const float* __restrict__ Wstep,
    const float* __restrict__ qbase, __half* __restrict__ qstep) {
  __shared__ float rows[8 * kE];
  int b = blockIdx.x;
  int n0 = blockIdx.y * 8;
  int tid = threadIdx.x;
  const float* Wbot = Wstep + kE * kE;

  for (int idx = tid; idx < 8 * kE; idx += 128)
    rows[idx] = ne[((size_t)b * kN + n0) * kE + idx];
  __syncthreads();

  float acc[8];
#pragma unroll
  for (int r = 0; r < 8; ++r) acc[r] = 0.f;
  for (int i = 0; i < kE; ++i) {
    float w = Wbot[i * kE + tid];
#pragma unroll
    for (int r = 0; r < 8; ++r) acc[r] += rows[r * kE + i] * w;
  }
  float qb = qbase[b * kE + tid];
#pragma unroll
  for (int r = 0; r < 8; ++r)
    qstep[((size_t)b * kN + n0 + r) * kE + tid] =
        __float2half((qb + acc[r]) * kQKScale);
}

// ---------------------------------------------------------------------------
// Kernel C: 999-step rollout, one 1024-thread block per batch element.
// Round-9 structure with the DS-pipe op stream halved (the invariant-8.2ms
// bottleneck): parts/ctx/Wmlp in packed f16 (b32 writes halved, wide
// aligned reads, fdot2 consumes packed pairs directly), rem reads cut
// 18->10 via register jn2 maintenance.  4 barriers/step.
// ---------------------------------------------------------------------------
__global__ __launch_bounds__(1024) void rollout_kernel(
    const float* __restrict__ Wmlp, const float* __restrict__ bmlp,
    const unsigned char* __restrict__ kq, const unsigned char* __restrict__ vq,
    const unsigned char* __restrict__ lkq, const __half* __restrict__ qstep,
    float* __restrict__ out) {
  __shared__ __align__(16) int rem[1024];          // SORTED live ids (padded)
  __shared__ __align__(16) unsigned parts_p[64][66];  // f16-pair partials
  __shared__ __align__(16) unsigned wm_p[kE][76];  // Wmlp f16 pairs, 39 KB
  __shared__ __align__(16) unsigned ctx_p[64];     // ctx as f16 pairs
  __shared__ float bm[kE];
  __shared__ __align__(16) __half xh[kE];
  __shared__ float redSum[16][kH];
  __shared__ __align__(16) float4 redPack[16];  // (m, ssum, argbits, -)

  int b = blockIdx.x;
  int tid = threadIdx.x;
  int lane = tid & 63;
  int wave = tid >> 6;
  int g = tid >> 3;  // node-group 0..127; slots j = g + 128r
  int t = tid & 7;   // head / uint4 chunk within row

  const unsigned char* kqb = kq + (size_t)b * kN * kE;
  const unsigned char* vqb = vq + (size_t)b * kN * kE;
  const unsigned char* lqb = lkq + (size_t)b * kN * kE;
  const __half* qsb = qstep + (size_t)b * kN * kE;

  // stage Wmlp as packed f16 pairs: wm_p[g][w] = {Wmlp[2w][g], Wmlp[2w+1][g]}
  {
    int gg = tid >> 3, q = tid & 7;
#pragma unroll
    for (int m = 0; m < 8; ++m) {
      int w = q * 8 + m;  // 0..63
      h2 pk = pkrtz(Wmlp[(2 * w) * kE + gg], Wmlp[(2 * w + 1) * kE + gg]);
      wm_p[gg][w] = __builtin_bit_cast(unsigned, pk);
    }
  }
  // init sorted live list (padded with valid ids for safe speculative reads)
  rem[tid] = (tid < kN - 1) ? tid + 1 : kN - 1;
  if (tid < kE) bm[tid] = bmlp[tid];

  // current action + its q row (prefetched into registers; node 0 first)
  int A = 0;
  uint4 qa, qb_;
  {
    const uint4* qr = (const uint4*)qsb;
    qa = qr[2 * t];
    qb_ = qr[2 * t + 1];
  }
  float total = 0.f;

  // register-resident slot ids: jn[r] = rem[j], jn2[r] = rem[j+1]
  int jn[8], jn2[8];
#pragma unroll
  for (int r = 0; r < 8; ++r) {
    int j = g + 128 * r;
    jn[r] = (j < kN - 1) ? j + 1 : -1;
    jn2[r] = (j + 1 < kN - 1) ? j + 2 : kN - 1;
  }

  barrier_lds();  // init visible

  for (int step = 0; step < kN - 1; ++step) {
    int R = kN - 1 - step;  // live count (deterministic)

    // ========== phase A: fused scores + ctx accumulation =================
    uint4 kb0, vb0, kb1, vb1;
    if (jn[0] >= 0) {
      kb0 = ((const uint4*)(kqb + (size_t)jn[0] * kE))[t];
      vb0 = ((const uint4*)(vqb + (size_t)jn[0] * kE))[t];
    }
    if (jn[1] >= 0) {
      kb1 = ((const uint4*)(kqb + (size_t)jn[1] * kE))[t];
      vb1 = ((const uint4*)(vqb + (size_t)jn[1] * kE))[t];
    }
    f2 q2[8];
    unpack16(qa, qb_, q2);  // 16 cvt, once per step
    f2 acc2[8];             // ctx accum as f32 pairs
#pragma unroll
    for (int i = 0; i < 8; ++i) acc2[i] = f2{0.f, 0.f};
    float den = 0.f;
#pragma unroll
    for (int r = 0; r < 8; ++r) {
      if (jn[r] < 0) break;  // sorted rem: deadness is monotone in r
      uint4 kk = (r & 1) ? kb1 : kb0;
      uint4 vv = (r & 1) ? vb1 : vb0;
      if (r + 2 < 8 && jn[r + 2] >= 0) {  // depth-2 slot pipeline
        if (r & 1) {
          kb1 = ((const uint4*)(kqb + (size_t)jn[r + 2] * kE))[t];
          vb1 = ((const uint4*)(vqb + (size_t)jn[r + 2] * kE))[t];
        } else {
          kb0 = ((const uint4*)(kqb + (size_t)jn[r + 2] * kE))[t];
          vb0 = ((const uint4*)(vqb + (size_t)jn[r + 2] * kE))[t];
        }
      }
      float s = dot16p(kk, q2);
      float hv = __expf(s);  // full head-t score (d=16): scores tiny
      den += hv;
      f2 hv2 = {hv, hv};
      vaccp(vv.x, hv2, acc2[0], acc2[1]);
      vaccp(vv.y, hv2, acc2[2], acc2[3]);
      vaccp(vv.z, hv2, acc2[4], acc2[5]);
      vaccp(vv.w, hv2, acc2[6], acc2[7]);
    }
    // lu prefetch (long cover: rest of A + B1 + C + D)
    uint4 lu[8];
#pragma unroll
    for (int r = 0; r < 8; ++r)
      if (jn[r] >= 0) lu[r] = ((const uint4*)(lqb + (size_t)jn[r] * kE))[t];
    // den: reduce over the 8 g-groups of this wave (preserve t = lane%8)
    den = dpp_addf<0x128>(den);
    den += __shfl_xor(den, 16);
    den += __shfl_xor(den, 32);
    if (lane < kH) redSum[wave][lane] = den;  // lane==t for lanes 0..7
    // acc: gw-pair fold (DPP), pack pairs to f16, 8x ds_write_b32
    {
      float av[16];
#pragma unroll
      for (int c = 0; c < 4; ++c) {
        av[4 * c + 0] = acc2[2 * c].x;
        av[4 * c + 1] = acc2[2 * c].y;
        av[4 * c + 2] = acc2[2 * c + 1].x;
        av[4 * c + 3] = acc2[2 * c + 1].y;
      }
#pragma unroll
      for (int i = 0; i < 16; ++i) av[i] = dpp_addf<0x128>(av[i]);
      if (((lane >> 3) & 1) == 0) {
        int chunk = wave * 4 + (lane >> 4);  // 0..63
#pragma unroll
        for (int i2 = 0; i2 < 8; ++i2) {
          h2 pk = pkrtz(av[2 * i2], av[2 * i2 + 1]);
          // row rho = i2*8 + t: write banks (16*i2 + 2t + chunk)&31 -> 2-way
          parts_p[i2 * 8 + t][chunk] = __builtin_bit_cast(unsigned, pk);
        }
      }
    }
    barrier_lds();  // B1: parts_p, redSum ready

    // ========== phase C: finalize ctx (all threads, pure-DPP tree) =======
    {
      int rho = tid >> 4;  // 0..63 : row of parts_p
      int cg = tid & 15;   // chunk group (4 chunks each)
      int h = rho & 7;     // head of this elem pair
      uint2 u01 = *(const uint2*)&parts_p[rho][4 * cg];
      uint2 u23 = *(const uint2*)&parts_p[rho][4 * cg + 2];
      f2 s = up2(u01.x) + up2(u01.y) + up2(u23.x) + up2(u23.y);
      float d = redSum[cg][h];
      float sx = s.x, sy = s.y;
      sx = dpp_addf<0xB1>(sx); sy = dpp_addf<0xB1>(sy); d = dpp_addf<0xB1>(d);
      sx = dpp_addf<0x4E>(sx); sy = dpp_addf<0x4E>(sy); d = dpp_addf<0x4E>(d);
      sx = dpp_addf<0x141>(sx); sy = dpp_addf<0x141>(sy); d = dpp_addf<0x141>(d);
      sx = dpp_addf<0x128>(sx); sy = dpp_addf<0x128>(sy); d = dpp_addf<0x128>(d);
      if (cg == 0) {
        float inv = 1.f / (d * kFP8Scale);
        int p = h * 8 + (rho >> 3);  // elem-pair index (elems 2p, 2p+1)
        ctx_p[p] = __builtin_bit_cast(unsigned, pkrtz(sx * inv, sy * inv));
      }
    }
    barrier_lds();  // B2: ctx_p ready

    // ========== phase D: x = (bm + ctx @ Wmlp) * kQKScale (fdot2) ========
    {
      uint4 c0 = ((const uint4*)ctx_p)[2 * t];
      uint4 c1 = ((const uint4*)ctx_p)[2 * t + 1];
      uint4 w0 = *(const uint4*)&wm_p[g][8 * t];
      uint4 w1 = *(const uint4*)&wm_p[g][8 * t + 4];
      unsigned cw[8] = {c0.x, c0.y, c0.z, c0.w, c1.x, c1.y, c1.z, c1.w};
      unsigned ww[8] = {w0.x, w0.y, w0.z, w0.w, w1.x, w1.y, w1.z, w1.w};
      float xacc = 0.f;
#pragma unroll
      for (int k = 0; k < 8; ++k)
        xacc = __builtin_amdgcn_fdot2(__builtin_bit_cast(h2, cw[k]),
                                      __builtin_bit_cast(h2, ww[k]), xacc,
                                      false);
      xacc = dpp_addf<0xB1>(xacc);
      xacc = dpp_addf<0x4E>(xacc);
      xacc = dpp_addf<0x141>(xacc);
      if (t == 0) xh[g] = __float2half((bm[g] + xacc) * kQKScale);
    }
    barrier_lds();  // B3: xh ready

    // ========== phase E: logits (lu in registers) + rem pre-reads ========
    int myv = rem[tid];
    int nxt = rem[(tid < 1023) ? tid + 1 : 1023];
    int rr2[8];  // rem[j+2] for next-step jn2 maintenance
#pragma unroll
    for (int r = 0; r < 8; ++r) {
      int j2 = g + 128 * r + 2;
      rr2[r] = rem[(j2 < 1024) ? j2 : 1023];
    }
    float m0 = -1e30f;
    int arg = 0x7fffffff;
    {
      f2 x2[8];
      uint4 xv0 = ((const uint4*)xh)[2 * t];
      uint4 xv1 = ((const uint4*)xh)[2 * t + 1];
      unpack16(xv0, xv1, x2);
#pragma unroll
      for (int r = 0; r < 8; ++r)
        if (jn[r] >= 0) {  // uniform within each octet (depends on g only)
          float s = dot16p(lu[r], x2);
          s = dpp_addf<0xB1>(s);
          s = dpp_addf<0x4E>(s);
          s = dpp_addf<0x141>(s);
          if (t == r) {  // lane t captures entry r
            m0 = fast_tanh(s) * 10.f;
            arg = jn[r];
          }
        }
    }
    // two-pass wave reduction: max+arg butterfly, then one exp + add tree
    float M = m0;
    int argM = arg;
    dpp_maxcomb<0xB1>(M, argM);
    dpp_maxcomb<0x4E>(M, argM);
    dpp_maxcomb<0x141>(M, argM);
    dpp_maxcomb<0x128>(M, argM);
#pragma unroll
    for (int off = 16; off <= 32; off <<= 1) {
      float mo = __shfl_xor(M, off);
      int ao = __shfl_xor(argM, off);
      maxcomb(M, argM, mo, ao);
    }
    float ex = __expf(m0 - M);  // dead lanes: exp(-huge) = 0
    ex = dpp_addf<0xB1>(ex);
    ex = dpp_addf<0x4E>(ex);
    ex = dpp_addf<0x141>(ex);
    ex = dpp_addf<0x128>(ex);
    ex += __shfl_xor(ex, 16);
    ex += __shfl_xor(ex, 32);
    if (lane == 0)
      redPack[wave] = make_float4(M, ex, __int_as_float(argM), 0.f);
    barrier_lds();  // B4: reductions ready; rem reads fenced from writes

    // ====== phase F: final combine, q prefetch, jn/jn2 patch, shift ======
    {
      float4 rp = redPack[lane & 15];
      float mw = rp.x, sw = rp.y;
      int aw = __float_as_int(rp.z);
      float Mf = mw;
      int Af = aw;
      dpp_maxcomb<0xB1>(Mf, Af);
      dpp_maxcomb<0x4E>(Mf, Af);
      dpp_maxcomb<0x141>(Mf, Af);
      dpp_maxcomb<0x128>(Mf, Af);
      float sc = sw * __expf(mw - Mf);  // dead waves contribute 0
      sc = dpp_addf<0xB1>(sc);
      sc = dpp_addf<0x4E>(sc);
      sc = dpp_addf<0x141>(sc);
      sc = dpp_addf<0x128>(sc);
      A = Af;
      total += -logf(sc);  // chosen logit == M => log_p[act] = -log S
      // prefetch next q row (every thread knows A; no barrier until B1')
      const uint4* qr = (const uint4*)(qsb + (size_t)A * kE);
      qa = qr[2 * t];
      qb_ = qr[2 * t + 1];
      // register patch (shift-left semantics):
      //   next_jn  = jn<A ? jn : jn2        (uses OLD jn2)
      //   next_jn2 = jn2<A ? jn2 : rem[j+2]
      int Rn = R - 1;
#pragma unroll
      for (int r = 0; r < 8; ++r) {
        int j = g + 128 * r;
        int nj = (jn[r] < A) ? jn[r] : jn2[r];
        jn[r] = (j < Rn) ? nj : -1;
        jn2[r] = (jn2[r] < A) ? jn2[r] : rr2[r];
      }
      // publish shift-remove (next read of rem is E', 3 barriers away)
      if (tid < R - 1 && myv >= A) rem[tid] = nxt;
    }
    // no end-of-step barrier needed
  }
  if (tid == 0) out[b] = total;
}

// ---------------------------------------------------------------------------
extern "C" void kernel_launch(void* const* d_in, const int* in_sizes, int n_in,
                              void* d_out, int out_size, void* d_ws,
                              size_t ws_size, hipStream_t stream) {
  const float* ne = (const float*)d_in[0];
  const float* ge = (const float*)d_in[1];
  const float* Wqkv = (const float*)d_in[2];
  const float* bqkv = (const float*)d_in[3];
  const float* Wfix = (const float*)d_in[4];
  const float* bfix = (const float*)d_in[5];
  const float* Wstep = (const float*)d_in[6];
  const float* bstep = (const float*)d_in[7];
  const float* Wmlp = (const float*)d_in[8];
  const float* bmlp = (const float*)d_in[9];
  float* out = (float*)d_out;

  size_t nkv = (size_t)kB * kN * kE;  // bytes per fp8 tensor
  unsigned char* kq = (unsigned char*)d_ws;
  unsigned char* vq = kq + nkv;
  unsigned char* lkq = vq + nkv;
  __half* qstep = (__half*)(lkq + nkv);  // 2*nkv bytes
  float* qbase = (float*)(qstep + nkv);  // 64 KB

  qkv_kernel<<<dim3(kB, (kN + 15) / 16), 384, 0, stream>>>(ne, Wqkv, bqkv, kq,
                                                           vq, lkq);
  qbase_kernel<<<kB, kE, 0, stream>>>(ne, ge, Wfix, bfix, Wstep, bstep, qbase);
  qstep_kernel<<<dim3(kB, kN / 8), 128, 0, stream>>>(ne, Wstep, qbase, qstep);
  rollout_kernel<<<kB, 1024, 0, stream>>>(Wmlp, bmlp, kq, vq, lkq, qstep, out);
}

// Round 11
// 8675.552 us; speedup vs baseline: 1.3383x; 1.3383x over previous
//
#include <hip/hip_runtime.h>
#include <hip/hip_fp16.h>

constexpr int kB = 128;
constexpr int kN = 1000;
constexpr int kE = 128;
constexpr int kH = 8;
constexpr float kFP8Scale = 64.f;         // fp8 values stored as v*64
constexpr float kQKScale = 0.25f / 64.f;  // 1/sqrt(16) folded with 1/64

typedef _Float16 h2 __attribute__((ext_vector_type(2)));
typedef float f2 __attribute__((ext_vector_type(2)));

__device__ __forceinline__ float fast_tanh(float x) {
  float t = __expf(2.f * x);
  return 1.f - 2.f / (t + 1.f);
}

__device__ __forceinline__ unsigned char enc_fp8(float v) {
  unsigned p = __builtin_amdgcn_cvt_pk_fp8_f32(v, v, 0, false);
  return (unsigned char)(p & 0xFF);
}

// packed fp8-pair dot: sacc += {fp8lo pair}*qa + {fp8hi pair}*qb  (v_pk_fma)
__device__ __forceinline__ void dotp(unsigned u, f2 qa, f2 qb, f2& sacc) {
  f2 lo = __builtin_amdgcn_cvt_pk_f32_fp8(u, false);
  f2 hi = __builtin_amdgcn_cvt_pk_f32_fp8(u, true);
  sacc += lo * qa;
  sacc += hi * qb;
}
// 16-elem fp8 dot (one uint4) against 16 f32 elems in q2[0..7] (f2 pairs).
__device__ __forceinline__ float dot16p(uint4 tq, const f2* q2) {
  f2 s = {0.f, 0.f};
  dotp(tq.x, q2[0], q2[1], s);
  dotp(tq.y, q2[2], q2[3], s);
  dotp(tq.z, q2[4], q2[5], s);
  dotp(tq.w, q2[6], q2[7], s);
  return s.x + s.y;
}
// packed V accumulate: a0 += hv2*{lo pair}; a1 += hv2*{hi pair}
__device__ __forceinline__ void vaccp(unsigned u, f2 hv2, f2& a0, f2& a1) {
  f2 lo = __builtin_amdgcn_cvt_pk_f32_fp8(u, false);
  f2 hi = __builtin_amdgcn_cvt_pk_f32_fp8(u, true);
  a0 += hv2 * lo;
  a1 += hv2 * hi;
}
// unpack 16 f16 (two uint4) -> 8 f2 of f32
__device__ __forceinline__ void unpack16(uint4 a, uint4 b, f2* q2) {
  unsigned w[8] = {a.x, a.y, a.z, a.w, b.x, b.y, b.z, b.w};
#pragma unroll
  for (int i = 0; i < 8; ++i) {
    h2 hh = __builtin_bit_cast(h2, w[i]);
    q2[i] = f2{(float)hh.x, (float)hh.y};
  }
}

// max+argmax combine; tie -> smaller node id (jnp.argmax semantics).
__device__ __forceinline__ void maxcomb(float& m, int& a, float mo, int ao) {
  bool take = (mo > m) || (mo == m && ao < a);
  m = take ? mo : m;
  a = take ? ao : a;
}

// ---- DPP cross-lane helpers (VALU pipe, not DS) ---------------------------
// 0xB1 = quad_perm xor1, 0x4E = quad_perm xor2, 0x141 = row_half_mirror
// (xor4-equiv within octet), 0x128 = row_ror:8 (xor8-equiv within 16 lanes).
template <int CTRL>
__device__ __forceinline__ float dpp_bcastf(float x) {
  return __builtin_bit_cast(
      float, __builtin_amdgcn_update_dpp(0, __builtin_bit_cast(int, x), CTRL,
                                         0xf, 0xf, true));
}
template <int CTRL>
__device__ __forceinline__ int dpp_bcasti(int x) {
  return __builtin_amdgcn_update_dpp(0, x, CTRL, 0xf, 0xf, true);
}
template <int CTRL>
__device__ __forceinline__ float dpp_addf(float x) {
  return x + dpp_bcastf<CTRL>(x);
}
template <int CTRL>
__device__ __forceinline__ void dpp_maxcomb(float& m, int& a) {
  float mo = dpp_bcastf<CTRL>(m);
  int ao = dpp_bcasti<CTRL>(a);
  maxcomb(m, a, mo, ao);
}

// LDS-only barrier: drains DS ops, leaves global register-loads in flight.
__device__ __forceinline__ void barrier_lds() {
  asm volatile("s_waitcnt lgkmcnt(0)" ::: "memory");
  __builtin_amdgcn_s_barrier();
  asm volatile("" ::: "memory");
}

// ---------------------------------------------------------------------------
// Kernel A: qkv projection -> fp8 (value*64) k / v / logit_k.
// ---------------------------------------------------------------------------
__global__ __launch_bounds__(384) void qkv_kernel(
    const float* __restrict__ ne, const float* __restrict__ Wqkv,
    const float* __restrict__ bqkv, unsigned char* __restrict__ kq,
    unsigned char* __restrict__ vq, unsigned char* __restrict__ lkq) {
  __shared__ float rows[16 * kE];
  int b = blockIdx.x;
  int n0 = blockIdx.y * 16;
  int ntile = min(16, kN - n0);
  int tid = threadIdx.x;

  for (int idx = tid; idx < ntile * kE; idx += 384)
    rows[idx] = ne[(b * kN + n0) * kE + idx];
  __syncthreads();

  int j = tid;  // 0..383
  float acc[16];
#pragma unroll
  for (int r = 0; r < 16; ++r) acc[r] = 0.f;
  for (int i = 0; i < kE; ++i) {
    float w = Wqkv[i * (3 * kE) + j];
#pragma unroll
    for (int r = 0; r < 16; ++r) acc[r] += rows[r * kE + i] * w;
  }
  float bias = bqkv[j];
  unsigned char* dst;
  int col;
  if (j < kE) { dst = kq; col = j; }
  else if (j < 2 * kE) { dst = vq; col = j - kE; }
  else { dst = lkq; col = j - 2 * kE; }
  for (int r = 0; r < ntile; ++r)
    dst[(size_t)(b * kN + n0 + r) * kE + col] =
        enc_fp8((acc[r] + bias) * kFP8Scale);
}

// ---------------------------------------------------------------------------
// Kernel B: qbase[b] = ge@Wfix + bfix + first@Wstep_top + bstep  (fp32)
// ---------------------------------------------------------------------------
__global__ __launch_bounds__(128) void qbase_kernel(
    const float* __restrict__ ne, const float* __restrict__ ge,
    const float* __restrict__ Wfix, const float* __restrict__ bfix,
    const float* __restrict__ Wstep, const float* __restrict__ bstep,
    float* __restrict__ qbase) {
  __shared__ float g[kE], f[kE];
  int b = blockIdx.x, e = threadIdx.x;
  g[e] = ge[b * kE + e];
  f[e] = ne[(size_t)b * kN * kE + e];  // node 0
  __syncthreads();
  float acc = bfix[e] + bstep[e];
  for (int i = 0; i < kE; ++i)
    acc += g[i] * Wfix[i * kE + e] + f[i] * Wstep[i * kE + e];
  qbase[b * kE + e] = acc;
}

// ---------------------------------------------------------------------------
// Kernel B2: qstep[b,n] = (qbase[b] + ne[b,n] @ Wbot) * kQKScale, f16.
// ---------------------------------------------------------------------------
__global__ __launch_bounds__(128) void qstep_kernel(
    const float* __restrict__ ne, const float* __restrict__ Wstep,
    const float* __restrict__ qbase, __half* __restrict__ qstep) {
  __shared__ float rows[8 * kE];
  int b = blockIdx.x;
  int n0 = blockIdx.y * 8;
  int tid = threadIdx.x;
  const float* Wbot = Wstep + kE * kE;

  for (int idx = tid; idx < 8 * kE; idx += 128)
    rows[idx] = ne[((size_t)b * kN + n0) * kE + idx];
  __syncthreads();

  float acc[8];
#pragma unroll
  for (int r = 0; r < 8; ++r) acc[r] = 0.f;
  for (int i = 0; i < kE; ++i) {
    float w = Wbot[i * kE + tid];
#pragma unroll
    for (int r = 0; r < 8; ++r) acc[r] += rows[r * kE + i] * w;
  }
  float qb = qbase[b * kE + tid];
#pragma unroll
  for (int r = 0; r < 8; ++r)
    qstep[((size_t)b * kN + n0 + r) * kE + tid] =
        __float2half((qb + acc[r]) * kQKScale);
}

// ---------------------------------------------------------------------------
// Kernel C: 999-step rollout, one 1024-thread block per batch element.
// REVERT to round-9 structure (best verified, 8.2 ms):
//  * head-alignment fusion (p·V in registers), packed v_pk_fma paths
//  * 4 barriers/step, register jn + local-patch maintenance
//  * two-pass max-then-sum reductions
// Round-10's f16-LDS packing is REVERTED (DS ops/conflicts halved but dur
// +36% — DS pipe proven not the limiter; packing added critical-path stall).
// Only delta vs round 9: phase F computes argmax first and issues the q-row
// load ~100cy earlier, before the denominator sum (the one cross-step
// dependency that cannot be prefetched).
// ---------------------------------------------------------------------------
__global__ __launch_bounds__(1024) void rollout_kernel(
    const float* __restrict__ Wmlp, const float* __restrict__ bmlp,
    const unsigned char* __restrict__ kq, const unsigned char* __restrict__ vq,
    const unsigned char* __restrict__ lkq, const __half* __restrict__ qstep,
    float* __restrict__ out) {
  __shared__ __align__(16) int rem[1024];       // SORTED live ids (padded)
  __shared__ __align__(16) float parts[kE][65]; // ctx chunk partials, 33 KB
  __shared__ __align__(16) float wmT[kE][140];  // wmT[g][i]=Wmlp[i][g], 70 KB
  __shared__ float bm[kE];
  __shared__ __align__(16) float ctx[kE];
  __shared__ __align__(16) __half xh[kE];
  __shared__ float redSum[16][kH];
  __shared__ __align__(16) float4 redPack[16];  // (m, ssum, argbits, -)

  int b = blockIdx.x;
  int tid = threadIdx.x;
  int lane = tid & 63;
  int wave = tid >> 6;
  int g = tid >> 3;  // node-group 0..127; slots j = g + 128r
  int t = tid & 7;   // head / uint4 chunk within row

  const unsigned char* kqb = kq + (size_t)b * kN * kE;
  const unsigned char* vqb = vq + (size_t)b * kN * kE;
  const unsigned char* lqb = lkq + (size_t)b * kN * kE;
  const __half* qsb = qstep + (size_t)b * kN * kE;

  // stage Wmlp transposed into LDS (one-time; coalesced reads)
#pragma unroll
  for (int m = 0; m < 16; ++m) {
    int idx = tid * 16 + m;  // 0..16383
    wmT[idx & 127][idx >> 7] = Wmlp[idx];
  }
  // init sorted live list (padded with valid ids for safe speculative reads)
  rem[tid] = (tid < kN - 1) ? tid + 1 : kN - 1;
  if (tid < kE) bm[tid] = bmlp[tid];

  // current action + its q row (prefetched into registers; node 0 first)
  int A = 0;
  uint4 qa, qb_;
  {
    const uint4* qr = (const uint4*)qsb;
    qa = qr[2 * t];
    qb_ = qr[2 * t + 1];
  }
  float total = 0.f;

  // step-0 jn (initial rem[j] = j+1), register resident
  int jn[8];
#pragma unroll
  for (int r = 0; r < 8; ++r) {
    int j = g + 128 * r;
    jn[r] = (j < kN - 1) ? j + 1 : -1;
  }

  barrier_lds();  // init visible

  for (int step = 0; step < kN - 1; ++step) {
    int R = kN - 1 - step;  // live count (deterministic)

    // ========== phase A: fused scores + ctx accumulation =================
    // K/V loads issue immediately (jn is register-resident, no rem reads)
    uint4 kb0, vb0, kb1, vb1;
    if (jn[0] >= 0) {
      kb0 = ((const uint4*)(kqb + (size_t)jn[0] * kE))[t];
      vb0 = ((const uint4*)(vqb + (size_t)jn[0] * kE))[t];
    }
    if (jn[1] >= 0) {
      kb1 = ((const uint4*)(kqb + (size_t)jn[1] * kE))[t];
      vb1 = ((const uint4*)(vqb + (size_t)jn[1] * kE))[t];
    }
    f2 q2[8];
    unpack16(qa, qb_, q2);  // 16 cvt, once per step
    f2 acc2[8];             // ctx accum as f32 pairs (elems 4c..4c+3 per c)
#pragma unroll
    for (int i = 0; i < 8; ++i) acc2[i] = f2{0.f, 0.f};
    float den = 0.f;
#pragma unroll
    for (int r = 0; r < 8; ++r) {
      if (jn[r] < 0) break;  // sorted rem: deadness is monotone in r
      uint4 kk = (r & 1) ? kb1 : kb0;
      uint4 vv = (r & 1) ? vb1 : vb0;
      if (r + 2 < 8 && jn[r + 2] >= 0) {  // depth-2 slot pipeline
        if (r & 1) {
          kb1 = ((const uint4*)(kqb + (size_t)jn[r + 2] * kE))[t];
          vb1 = ((const uint4*)(vqb + (size_t)jn[r + 2] * kE))[t];
        } else {
          kb0 = ((const uint4*)(kqb + (size_t)jn[r + 2] * kE))[t];
          vb0 = ((const uint4*)(vqb + (size_t)jn[r + 2] * kE))[t];
        }
      }
      float s = dot16p(kk, q2);
      float hv = __expf(s);  // full head-t score (d=16): scores tiny
      den += hv;
      f2 hv2 = {hv, hv};
      vaccp(vv.x, hv2, acc2[0], acc2[1]);
      vaccp(vv.y, hv2, acc2[2], acc2[3]);
      vaccp(vv.z, hv2, acc2[4], acc2[5]);
      vaccp(vv.w, hv2, acc2[6], acc2[7]);
    }
    // lu prefetch (long cover: rest of A + B1 + C + D)
    uint4 lu[8];
#pragma unroll
    for (int r = 0; r < 8; ++r)
      if (jn[r] >= 0) lu[r] = ((const uint4*)(lqb + (size_t)jn[r] * kE))[t];
    // den: reduce over the 8 g-groups of this wave (preserve t = lane%8)
    den = dpp_addf<0x128>(den);
    den += __shfl_xor(den, 16);
    den += __shfl_xor(den, 32);
    if (lane < kH) redSum[wave][lane] = den;  // lane==t for lanes 0..7
    // acc: unpack to scalars, gw-pair fold (VALU), write 64-chunk parts
    {
      float av[16];
#pragma unroll
      for (int c = 0; c < 4; ++c) {
        av[4 * c + 0] = acc2[2 * c].x;
        av[4 * c + 1] = acc2[2 * c].y;
        av[4 * c + 2] = acc2[2 * c + 1].x;
        av[4 * c + 3] = acc2[2 * c + 1].y;
      }
#pragma unroll
      for (int i = 0; i < 16; ++i) av[i] = dpp_addf<0x128>(av[i]);
      if (((lane >> 3) & 1) == 0) {
        int chunk = wave * 4 + (lane >> 4);  // 0..63
#pragma unroll
        for (int i = 0; i < 16; ++i)
          parts[t * 16 + i][(chunk + 4 * t) & 63] = av[i];  // bank-injective
      }
    }
    barrier_lds();  // B1: parts, redSum ready

    // ========== phase C: finalize ctx (all threads, DPP octet tree) ======
    {
      int e = tid >> 3, k = tid & 7, hh = e >> 4;
      float s = 0.f;
#pragma unroll
      for (int m = 0; m < 8; ++m)
        s += parts[e][((8 * k + m) + 4 * hh) & 63];
      float d = redSum[2 * k][hh] + redSum[2 * k + 1][hh];
      s = dpp_addf<0xB1>(s);
      s = dpp_addf<0x4E>(s);
      s = dpp_addf<0x141>(s);
      d = dpp_addf<0xB1>(d);
      d = dpp_addf<0x4E>(d);
      d = dpp_addf<0x141>(d);
      if (k == 0) ctx[e] = s / (d * kFP8Scale);
    }
    barrier_lds();  // B2: ctx ready

    // ========== phase D: x = (bm + ctx @ Wmlp) * kQKScale (wm from LDS) ==
    {
      float xacc = 0.f;
      const float4* c4 = (const float4*)(ctx + t * 16);
      const float4* w4 = (const float4*)(&wmT[g][t * 16]);
#pragma unroll
      for (int k4 = 0; k4 < 4; ++k4) {
        float4 cv = c4[k4];
        float4 wv = w4[k4];
        xacc += cv.x * wv.x + cv.y * wv.y + cv.z * wv.z + cv.w * wv.w;
      }
      xacc = dpp_addf<0xB1>(xacc);
      xacc = dpp_addf<0x4E>(xacc);
      xacc = dpp_addf<0x141>(xacc);
      if (t == 0) xh[g] = __float2half((bm[g] + xacc) * kQKScale);
    }
    barrier_lds();  // B3: xh ready

    // ========== phase E: logits (lu in registers) + rem pre-reads ========
    // rem reads for shift-remove AND next-step jn patch happen HERE
    // (pre-B4); B4 fences them from the phase-F writes.
    int myv = rem[tid];
    int nxt = rem[(tid < 1023) ? tid + 1 : 1023];
    int pra[8], prb[8];
#pragma unroll
    for (int r = 0; r < 8; ++r) {
      int j = g + 128 * r;  // <= 1023
      pra[r] = rem[j];
      prb[r] = rem[(j < 1023) ? j + 1 : 1023];
    }
    float m0 = -1e30f;
    int arg = 0x7fffffff;
    {
      f2 x2[8];
      uint4 xv0 = ((const uint4*)xh)[2 * t];
      uint4 xv1 = ((const uint4*)xh)[2 * t + 1];
      unpack16(xv0, xv1, x2);
#pragma unroll
      for (int r = 0; r < 8; ++r)
        if (jn[r] >= 0) {  // uniform within each octet (depends on g only)
          float s = dot16p(lu[r], x2);
          s = dpp_addf<0xB1>(s);
          s = dpp_addf<0x4E>(s);
          s = dpp_addf<0x141>(s);
          if (t == r) {  // lane t captures entry r
            m0 = fast_tanh(s) * 10.f;
            arg = jn[r];
          }
        }
    }
    // two-pass wave reduction: (1) max+arg butterfly (no exp), (2) one exp
    // per lane + add butterfly.
    float M = m0;
    int argM = arg;
    dpp_maxcomb<0xB1>(M, argM);
    dpp_maxcomb<0x4E>(M, argM);
    dpp_maxcomb<0x141>(M, argM);
    dpp_maxcomb<0x128>(M, argM);
#pragma unroll
    for (int off = 16; off <= 32; off <<= 1) {
      float mo = __shfl_xor(M, off);
      int ao = __shfl_xor(argM, off);
      maxcomb(M, argM, mo, ao);
    }
    float ex = __expf(m0 - M);  // dead lanes: exp(-huge) = 0
    ex = dpp_addf<0xB1>(ex);
    ex = dpp_addf<0x4E>(ex);
    ex = dpp_addf<0x141>(ex);
    ex = dpp_addf<0x128>(ex);
    ex += __shfl_xor(ex, 16);
    ex += __shfl_xor(ex, 32);
    if (lane == 0)
      redPack[wave] = make_float4(M, ex, __int_as_float(argM), 0.f);
    barrier_lds();  // B4: reductions ready; rem reads fenced from writes

    // ====== phase F: argmax FIRST (q issues early), then denominator =====
    {
      float4 rp = redPack[lane & 15];
      float mw = rp.x, sw = rp.y;
      int aw = __float_as_int(rp.z);
      // pass 1: block argmax — gets A as early as possible
      float Mf = mw;
      int Af = aw;
      dpp_maxcomb<0xB1>(Mf, Af);
      dpp_maxcomb<0x4E>(Mf, Af);
      dpp_maxcomb<0x141>(Mf, Af);
      dpp_maxcomb<0x128>(Mf, Af);
      A = Af;
      // issue next q row NOW (latency hides under the sum pass + next A)
      const uint4* qr = (const uint4*)(qsb + (size_t)A * kE);
      qa = qr[2 * t];
      qb_ = qr[2 * t + 1];
      // pass 2: block denominator
      float sc = sw * __expf(mw - Mf);  // dead waves contribute 0
      sc = dpp_addf<0xB1>(sc);
      sc = dpp_addf<0x4E>(sc);
      sc = dpp_addf<0x141>(sc);
      sc = dpp_addf<0x128>(sc);
      total += -logf(sc);  // chosen logit == M => log_p[act] = -log S
      // next-step jn via locally patched sorted rem:
      // next[j] = old[j] < A ? old[j] : old[j+1]  (shift-left semantics)
      int Rn = R - 1;
#pragma unroll
      for (int r = 0; r < 8; ++r) {
        int j = g + 128 * r;
        jn[r] = (j < Rn) ? ((pra[r] < A) ? pra[r] : prb[r]) : -1;
      }
      // publish shift-remove for future steps (read again only in E',
      // which is fenced by B1'/B2'/B3')
      if (tid < R - 1 && myv >= A) rem[tid] = nxt;
    }
    // no end-of-step barrier: rem is next read in phase E' (3 barriers away)
  }
  if (tid == 0) out[b] = total;
}

// ---------------------------------------------------------------------------
extern "C" void kernel_launch(void* const* d_in, const int* in_sizes, int n_in,
                              void* d_out, int out_size, void* d_ws,
                              size_t ws_size, hipStream_t stream) {
  const float* ne = (const float*)d_in[0];
  const float* ge = (const float*)d_in[1];
  const float* Wqkv = (const float*)d_in[2];
  const float* bqkv = (const float*)d_in[3];
  const float* Wfix = (const float*)d_in[4];
  const float* bfix = (const float*)d_in[5];
  const float* Wstep = (const float*)d_in[6];
  const float* bstep = (const float*)d_in[7];
  const float* Wmlp = (const float*)d_in[8];
  const float* bmlp = (const float*)d_in[9];
  float* out = (float*)d_out;

  size_t nkv = (size_t)kB * kN * kE;  // bytes per fp8 tensor
  unsigned char* kq = (unsigned char*)d_ws;
  unsigned char* vq = kq + nkv;
  unsigned char* lkq = vq + nkv;
  __half* qstep = (__half*)(lkq + nkv);  // 2*nkv bytes
  float* qbase = (float*)(qstep + nkv);  // 64 KB

  qkv_kernel<<<dim3(kB, (kN + 15) / 16), 384, 0, stream>>>(ne, Wqkv, bqkv, kq,
                                                           vq, lkq);
  qbase_kernel<<<kB, kE, 0, stream>>>(ne, ge, Wfix, bfix, Wstep, bstep, qbase);
  qstep_kernel<<<dim3(kB, kN / 8), 128, 0, stream>>>(ne, Wstep, qbase, qstep);
  rollout_kernel<<<kB, 1024, 0, stream>>>(Wmlp, bmlp, kq, vq, lkq, qstep, out);
}

// Round 12
// 7299.358 us; speedup vs baseline: 1.5906x; 1.1885x over previous
//
#include <hip/hip_runtime.h>
#include <hip/hip_fp16.h>

constexpr int kB = 128;
constexpr int kN = 1000;
constexpr int kE = 128;
constexpr int kH = 8;
constexpr float kFP8Scale = 64.f;         // fp8 values stored as v*64
constexpr float kQKScale = 0.25f / 64.f;  // 1/sqrt(16) folded with 1/64

typedef _Float16 h2 __attribute__((ext_vector_type(2)));
typedef float f2 __attribute__((ext_vector_type(2)));

__device__ __forceinline__ float fast_tanh(float x) {
  float t = __expf(2.f * x);
  return 1.f - 2.f / (t + 1.f);
}

__device__ __forceinline__ unsigned char enc_fp8(float v) {
  unsigned p = __builtin_amdgcn_cvt_pk_fp8_f32(v, v, 0, false);
  return (unsigned char)(p & 0xFF);
}

// packed fp8-pair dot: sacc += {fp8lo pair}*qa + {fp8hi pair}*qb  (v_pk_fma)
__device__ __forceinline__ void dotp(unsigned u, f2 qa, f2 qb, f2& sacc) {
  f2 lo = __builtin_amdgcn_cvt_pk_f32_fp8(u, false);
  f2 hi = __builtin_amdgcn_cvt_pk_f32_fp8(u, true);
  sacc += lo * qa;
  sacc += hi * qb;
}
// 16-elem fp8 dot (one uint4) against 16 f32 elems in q2[0..7] (f2 pairs).
__device__ __forceinline__ float dot16p(uint4 tq, const f2* q2) {
  f2 s = {0.f, 0.f};
  dotp(tq.x, q2[0], q2[1], s);
  dotp(tq.y, q2[2], q2[3], s);
  dotp(tq.z, q2[4], q2[5], s);
  dotp(tq.w, q2[6], q2[7], s);
  return s.x + s.y;
}
// packed V accumulate: a0 += hv2*{lo pair}; a1 += hv2*{hi pair}
__device__ __forceinline__ void vaccp(unsigned u, f2 hv2, f2& a0, f2& a1) {
  f2 lo = __builtin_amdgcn_cvt_pk_f32_fp8(u, false);
  f2 hi = __builtin_amdgcn_cvt_pk_f32_fp8(u, true);
  a0 += hv2 * lo;
  a1 += hv2 * hi;
}
// unpack 16 f16 (two uint4) -> 8 f2 of f32
__device__ __forceinline__ void unpack16(uint4 a, uint4 b, f2* q2) {
  unsigned w[8] = {a.x, a.y, a.z, a.w, b.x, b.y, b.z, b.w};
#pragma unroll
  for (int i = 0; i < 8; ++i) {
    h2 hh = __builtin_bit_cast(h2, w[i]);
    q2[i] = f2{(float)hh.x, (float)hh.y};
  }
}

// max+argmax combine; tie -> smaller node id (jnp.argmax semantics).
__device__ __forceinline__ void maxcomb(float& m, int& a, float mo, int ao) {
  bool take = (mo > m) || (mo == m && ao < a);
  m = take ? mo : m;
  a = take ? ao : a;
}

// ---- DPP cross-lane helpers (VALU pipe, not DS) ---------------------------
// 0xB1 = quad_perm xor1, 0x4E = quad_perm xor2, 0x141 = row_half_mirror
// (xor4-equiv within octet), 0x128 = row_ror:8 (xor8-equiv within 16 lanes).
template <int CTRL>
__device__ __forceinline__ float dpp_bcastf(float x) {
  return __builtin_bit_cast(
      float, __builtin_amdgcn_update_dpp(0, __builtin_bit_cast(int, x), CTRL,
                                         0xf, 0xf, true));
}
template <int CTRL>
__device__ __forceinline__ int dpp_bcasti(int x) {
  return __builtin_amdgcn_update_dpp(0, x, CTRL, 0xf, 0xf, true);
}
template <int CTRL>
__device__ __forceinline__ float dpp_addf(float x) {
  return x + dpp_bcastf<CTRL>(x);
}
template <int CTRL>
__device__ __forceinline__ void dpp_maxcomb(float& m, int& a) {
  float mo = dpp_bcastf<CTRL>(m);
  int ao = dpp_bcasti<CTRL>(a);
  maxcomb(m, a, mo, ao);
}

// LDS-only barrier: drains DS ops, leaves global register-loads in flight.
__device__ __forceinline__ void barrier_lds() {
  asm volatile("s_waitcnt lgkmcnt(0)" ::: "memory");
  __builtin_amdgcn_s_barrier();
  asm volatile("" ::: "memory");
}

// ---------------------------------------------------------------------------
// Kernel A: qkv projection -> fp8 (value*64) k / v.  (logit_k is no longer
// materialized — the logits matvec is folded into M2, see w3/m2 kernels.)
// ---------------------------------------------------------------------------
__global__ __launch_bounds__(256) void qkv_kernel(
    const float* __restrict__ ne, const float* __restrict__ Wqkv,
    const float* __restrict__ bqkv, unsigned char* __restrict__ kq,
    unsigned char* __restrict__ vq) {
  __shared__ float rows[16 * kE];
  int b = blockIdx.x;
  int n0 = blockIdx.y * 16;
  int ntile = min(16, kN - n0);
  int tid = threadIdx.x;

  for (int idx = tid; idx < ntile * kE; idx += 256)
    rows[idx] = ne[(b * kN + n0) * kE + idx];
  __syncthreads();

  int j = tid;  // 0..255 (k and v columns only)
  float acc[16];
#pragma unroll
  for (int r = 0; r < 16; ++r) acc[r] = 0.f;
  for (int i = 0; i < kE; ++i) {
    float w = Wqkv[i * (3 * kE) + j];
#pragma unroll
    for (int r = 0; r < 16; ++r) acc[r] += rows[r * kE + i] * w;
  }
  float bias = bqkv[j];
  unsigned char* dst;
  int col;
  if (j < kE) { dst = kq; col = j; }
  else { dst = vq; col = j - kE; }
  for (int r = 0; r < ntile; ++r)
    dst[(size_t)(b * kN + n0 + r) * kE + col] =
        enc_fp8((acc[r] + bias) * kFP8Scale);
}

// ---------------------------------------------------------------------------
// Kernel W3 (batch-independent, tiny): W3[gin][i] = sum_g Wlk[gin][g]*Wmlp[i][g]
// b3[i] = sum_g blk[g]*Wmlp[i][g];  w4[gin] = sum_g Wlk[gin][g]*bm[g];
// c4 = sum_g blk[g]*bm[g].   (Wlk = Wqkv[:, 2E:3E], blk = bqkv[2E:3E])
// ---------------------------------------------------------------------------
__global__ __launch_bounds__(128) void w3_kernel(
    const float* __restrict__ Wqkv, const float* __restrict__ bqkv,
    const float* __restrict__ Wmlp, const float* __restrict__ bmlp,
    float* __restrict__ W3, float* __restrict__ b3, float* __restrict__ w4,
    float* __restrict__ c4) {
  __shared__ float lk_s[kE];
  __shared__ float red[kE];
  int gin = blockIdx.x, i = threadIdx.x;
  lk_s[i] = Wqkv[gin * (3 * kE) + 2 * kE + i];
  __syncthreads();
  float s = 0.f;
  for (int g = 0; g < kE; ++g) s += lk_s[g] * Wmlp[i * kE + g];
  W3[gin * kE + i] = s;
  red[i] = lk_s[i] * bmlp[i];
  __syncthreads();
  if (i == 0) {
    float t = 0.f;
    for (int g = 0; g < kE; ++g) t += red[g];
    w4[gin] = t;
  }
  if (gin == 0) {
    float t2 = 0.f;
    for (int g = 0; g < kE; ++g) t2 += bqkv[2 * kE + g] * Wmlp[i * kE + g];
    b3[i] = t2;
    if (i == 0) {
      float t3 = 0.f;
      for (int g = 0; g < kE; ++g) t3 += bqkv[2 * kE + g] * bmlp[g];
      c4[0] = t3;
    }
  }
}

// ---------------------------------------------------------------------------
// Kernel M2: M2[b][j][i] = ne[b,j]@W3 + b3  -> fp8 (*64).
//            bB[b][j] = 0.25*(ne[b,j]·w4 + c4)  (pre-scaled logit bias)
// ---------------------------------------------------------------------------
__global__ __launch_bounds__(128) void m2_kernel(
    const float* __restrict__ ne, const float* __restrict__ W3,
    const float* __restrict__ b3, const float* __restrict__ w4,
    const float* __restrict__ c4, unsigned char* __restrict__ m2q,
    float* __restrict__ bB) {
  __shared__ float rows[8 * kE];
  __shared__ float w4_s[kE];
  int b = blockIdx.x;
  int n0 = blockIdx.y * 8;
  int tid = threadIdx.x;

  for (int idx = tid; idx < 8 * kE; idx += 128)
    rows[idx] = ne[((size_t)b * kN + n0) * kE + idx];
  w4_s[tid] = w4[tid];
  __syncthreads();

  float acc[8];
#pragma unroll
  for (int r = 0; r < 8; ++r) acc[r] = 0.f;
  for (int gin = 0; gin < kE; ++gin) {
    float w = W3[gin * kE + tid];
#pragma unroll
    for (int r = 0; r < 8; ++r) acc[r] += rows[r * kE + gin] * w;
  }
  float bi = b3[tid];
#pragma unroll
  for (int r = 0; r < 8; ++r)
    m2q[(size_t)(b * kN + n0 + r) * kE + tid] =
        enc_fp8((acc[r] + bi) * kFP8Scale);
  if (tid < 8) {
    float s = c4[0];
    for (int g = 0; g < kE; ++g) s += rows[tid * kE + g] * w4_s[g];
    bB[b * kN + n0 + tid] = 0.25f * s;
  }
}

// ---------------------------------------------------------------------------
// Kernel B: qbase[b] = ge@Wfix + bfix + first@Wstep_top + bstep  (fp32)
// ---------------------------------------------------------------------------
__global__ __launch_bounds__(128) void qbase_kernel(
    const float* __restrict__ ne, const float* __restrict__ ge,
    const float* __restrict__ Wfix, const float* __restrict__ bfix,
    const float* __restrict__ Wstep, const float* __restrict__ bstep,
    float* __restrict__ qbase) {
  __shared__ float g[kE], f[kE];
  int b = blockIdx.x, e = threadIdx.x;
  g[e] = ge[b * kE + e];
  f[e] = ne[(size_t)b * kN * kE + e];  // node 0
  __syncthreads();
  float acc = bfix[e] + bstep[e];
  for (int i = 0; i < kE; ++i)
    acc += g[i] * Wfix[i * kE + e] + f[i] * Wstep[i * kE + e];
  qbase[b * kE + e] = acc;
}

// ---------------------------------------------------------------------------
// Kernel B2: qstep[b,n] = (qbase[b] + ne[b,n] @ Wbot) * kQKScale, f16.
// ---------------------------------------------------------------------------
__global__ __launch_bounds__(128) void qstep_kernel(
    const float* __restrict__ ne, const float* __restrict__ Wstep,
    const float* __restrict__ qbase, __half* __restrict__ qstep) {
  __shared__ float rows[8 * kE];
  int b = blockIdx.x;
  int n0 = blockIdx.y * 8;
  int tid = threadIdx.x;
  const float* Wbot = Wstep + kE * kE;

  for (int idx = tid; idx < 8 * kE; idx += 128)
    rows[idx] = ne[((size_t)b * kN + n0) * kE + idx];
  __syncthreads();

  float acc[8];
#pragma unroll
  for (int r = 0; r < 8; ++r) acc[r] = 0.f;
  for (int i = 0; i < kE; ++i) {
    float w = Wbot[i * kE + tid];
#pragma unroll
    for (int r = 0; r < 8; ++r) acc[r] += rows[r * kE + i] * w;
  }
  float qb = qbase[b * kE + tid];
#pragma unroll
  for (int r = 0; r < 8; ++r)
    qstep[((size_t)b * kN + n0 + r) * kE + tid] =
        __float2half((qb + acc[r]) * kQKScale);
}

// ---------------------------------------------------------------------------
// Kernel C: 999-step rollout, one 1024-thread block per batch element.
// Round-11 structure MINUS phase D: the x=ctx@Wmlp matvec is algebraically
// folded into precomputed M2 (logit_j = kQKScale*(ctx·M2_j*64) + bB_j), so
// the step chain is A -> B1 -> C -> B2 -> E -> B3 -> F: 3 barriers/step
// (was 4), no wmT (70KB LDS freed), no xh round-trip.
// ---------------------------------------------------------------------------
__global__ __launch_bounds__(1024) void rollout_kernel(
    const unsigned char* __restrict__ kq, const unsigned char* __restrict__ vq,
    const unsigned char* __restrict__ m2q, const __half* __restrict__ qstep,
    const float* __restrict__ bB, float* __restrict__ out) {
  __shared__ __align__(16) int rem[1024];       // SORTED live ids (padded)
  __shared__ __align__(16) float parts[kE][65]; // ctx chunk partials, 33 KB
  __shared__ __align__(16) float bb_s[1024];    // 0.25*(bm·LK_j), 4 KB
  __shared__ __align__(16) float ctx[kE];
  __shared__ float redSum[16][kH];
  __shared__ __align__(16) float4 redPack[16];  // (m, ssum, argbits, -)

  int b = blockIdx.x;
  int tid = threadIdx.x;
  int lane = tid & 63;
  int wave = tid >> 6;
  int g = tid >> 3;  // node-group 0..127; slots j = g + 128r
  int t = tid & 7;   // head / uint4 chunk within row

  const unsigned char* kqb = kq + (size_t)b * kN * kE;
  const unsigned char* vqb = vq + (size_t)b * kN * kE;
  const unsigned char* mqb = m2q + (size_t)b * kN * kE;
  const __half* qsb = qstep + (size_t)b * kN * kE;

  // stage per-batch logit biases (read once per step per thread)
  if (tid < kN) bb_s[tid] = bB[(size_t)b * kN + tid];
  // init sorted live list (padded with valid ids for safe speculative reads)
  rem[tid] = (tid < kN - 1) ? tid + 1 : kN - 1;

  // current action + its q row (prefetched into registers; node 0 first)
  int A = 0;
  uint4 qa, qb_;
  {
    const uint4* qr = (const uint4*)qsb;
    qa = qr[2 * t];
    qb_ = qr[2 * t + 1];
  }
  float total = 0.f;

  // step-0 jn (initial rem[j] = j+1), register resident
  int jn[8];
#pragma unroll
  for (int r = 0; r < 8; ++r) {
    int j = g + 128 * r;
    jn[r] = (j < kN - 1) ? j + 1 : -1;
  }

  barrier_lds();  // init visible

  for (int step = 0; step < kN - 1; ++step) {
    int R = kN - 1 - step;  // live count (deterministic)

    // ========== phase A: fused scores + ctx accumulation =================
    // K/V loads issue immediately (jn is register-resident, no rem reads)
    uint4 kb0, vb0, kb1, vb1;
    if (jn[0] >= 0) {
      kb0 = ((const uint4*)(kqb + (size_t)jn[0] * kE))[t];
      vb0 = ((const uint4*)(vqb + (size_t)jn[0] * kE))[t];
    }
    if (jn[1] >= 0) {
      kb1 = ((const uint4*)(kqb + (size_t)jn[1] * kE))[t];
      vb1 = ((const uint4*)(vqb + (size_t)jn[1] * kE))[t];
    }
    f2 q2[8];
    unpack16(qa, qb_, q2);  // 16 cvt, once per step
    f2 acc2[8];             // ctx accum as f32 pairs (elems 4c..4c+3 per c)
#pragma unroll
    for (int i = 0; i < 8; ++i) acc2[i] = f2{0.f, 0.f};
    float den = 0.f;
#pragma unroll
    for (int r = 0; r < 8; ++r) {
      if (jn[r] < 0) break;  // sorted rem: deadness is monotone in r
      uint4 kk = (r & 1) ? kb1 : kb0;
      uint4 vv = (r & 1) ? vb1 : vb0;
      if (r + 2 < 8 && jn[r + 2] >= 0) {  // depth-2 slot pipeline
        if (r & 1) {
          kb1 = ((const uint4*)(kqb + (size_t)jn[r + 2] * kE))[t];
          vb1 = ((const uint4*)(vqb + (size_t)jn[r + 2] * kE))[t];
        } else {
          kb0 = ((const uint4*)(kqb + (size_t)jn[r + 2] * kE))[t];
          vb0 = ((const uint4*)(vqb + (size_t)jn[r + 2] * kE))[t];
        }
      }
      float s = dot16p(kk, q2);
      float hv = __expf(s);  // full head-t score (d=16): scores tiny
      den += hv;
      f2 hv2 = {hv, hv};
      vaccp(vv.x, hv2, acc2[0], acc2[1]);
      vaccp(vv.y, hv2, acc2[2], acc2[3]);
      vaccp(vv.z, hv2, acc2[4], acc2[5]);
      vaccp(vv.w, hv2, acc2[6], acc2[7]);
    }
    // M2 row prefetch (cover: rest of A + B1 + C; consumed in E)
    uint4 mu[8];
#pragma unroll
    for (int r = 0; r < 8; ++r)
      if (jn[r] >= 0) mu[r] = ((const uint4*)(mqb + (size_t)jn[r] * kE))[t];
    // den: reduce over the 8 g-groups of this wave (preserve t = lane%8)
    den = dpp_addf<0x128>(den);
    den += __shfl_xor(den, 16);
    den += __shfl_xor(den, 32);
    if (lane < kH) redSum[wave][lane] = den;  // lane==t for lanes 0..7
    // acc: unpack to scalars, gw-pair fold (VALU), write 64-chunk parts
    {
      float av[16];
#pragma unroll
      for (int c = 0; c < 4; ++c) {
        av[4 * c + 0] = acc2[2 * c].x;
        av[4 * c + 1] = acc2[2 * c].y;
        av[4 * c + 2] = acc2[2 * c + 1].x;
        av[4 * c + 3] = acc2[2 * c + 1].y;
      }
#pragma unroll
      for (int i = 0; i < 16; ++i) av[i] = dpp_addf<0x128>(av[i]);
      if (((lane >> 3) & 1) == 0) {
        int chunk = wave * 4 + (lane >> 4);  // 0..63
#pragma unroll
        for (int i = 0; i < 16; ++i)
          parts[t * 16 + i][(chunk + 4 * t) & 63] = av[i];  // bank-injective
      }
    }
    barrier_lds();  // B1: parts, redSum ready

    // ========== phase C: finalize ctx (all threads, DPP octet tree) ======
    {
      int e = tid >> 3, k = tid & 7, hh = e >> 4;
      float s = 0.f;
#pragma unroll
      for (int m = 0; m < 8; ++m)
        s += parts[e][((8 * k + m) + 4 * hh) & 63];
      float d = redSum[2 * k][hh] + redSum[2 * k + 1][hh];
      s = dpp_addf<0xB1>(s);
      s = dpp_addf<0x4E>(s);
      s = dpp_addf<0x141>(s);
      d = dpp_addf<0xB1>(d);
      d = dpp_addf<0x4E>(d);
      d = dpp_addf<0x141>(d);
      if (k == 0) ctx[e] = s / (d * kFP8Scale);
    }
    barrier_lds();  // B2: ctx ready

    // ========== phase E: logits via M2 (mu in registers) + rem pre-reads =
    // rem reads for shift-remove AND next-step jn patch happen HERE
    // (pre-B3); B3 fences them from the phase-F writes.
    int myv = rem[tid];
    int nxt = rem[(tid < 1023) ? tid + 1 : 1023];
    int pra[8], prb[8];
#pragma unroll
    for (int r = 0; r < 8; ++r) {
      int j = g + 128 * r;  // <= 1023
      pra[r] = rem[j];
      prb[r] = rem[(j < 1023) ? j + 1 : 1023];
    }
    float m0raw = 0.f;
    int arg = 0x7fffffff;
    {
      f2 c2[8];
      const float4* cc = (const float4*)(ctx + t * 16);
#pragma unroll
      for (int k4 = 0; k4 < 4; ++k4) {
        float4 cv = cc[k4];
        c2[2 * k4] = f2{cv.x, cv.y};
        c2[2 * k4 + 1] = f2{cv.z, cv.w};
      }
#pragma unroll
      for (int r = 0; r < 8; ++r)
        if (jn[r] >= 0) {  // uniform within each octet (depends on g only)
          float s = dot16p(mu[r], c2);
          s = dpp_addf<0xB1>(s);
          s = dpp_addf<0x4E>(s);
          s = dpp_addf<0x141>(s);
          if (t == r) {  // lane t captures entry r (raw dot)
            m0raw = s;
            arg = jn[r];
          }
        }
    }
    // bias + tanh once per thread (its captured entry), then two-pass
    // wave reduction: max+arg butterfly, then one exp + add butterfly.
    float m0 = -1e30f;
    if (arg != 0x7fffffff)
      m0 = fast_tanh(kQKScale * m0raw + bb_s[arg]) * 10.f;
    float M = m0;
    int argM = arg;
    dpp_maxcomb<0xB1>(M, argM);
    dpp_maxcomb<0x4E>(M, argM);
    dpp_maxcomb<0x141>(M, argM);
    dpp_maxcomb<0x128>(M, argM);
#pragma unroll
    for (int off = 16; off <= 32; off <<= 1) {
      float mo = __shfl_xor(M, off);
      int ao = __shfl_xor(argM, off);
      maxcomb(M, argM, mo, ao);
    }
    float ex = __expf(m0 - M);  // dead lanes: exp(-huge) = 0
    ex = dpp_addf<0xB1>(ex);
    ex = dpp_addf<0x4E>(ex);
    ex = dpp_addf<0x141>(ex);
    ex = dpp_addf<0x128>(ex);
    ex += __shfl_xor(ex, 16);
    ex += __shfl_xor(ex, 32);
    if (lane == 0)
      redPack[wave] = make_float4(M, ex, __int_as_float(argM), 0.f);
    barrier_lds();  // B3: reductions ready; rem reads fenced from writes

    // ====== phase F: argmax FIRST (q issues early), then denominator =====
    {
      float4 rp = redPack[lane & 15];
      float mw = rp.x, sw = rp.y;
      int aw = __float_as_int(rp.z);
      // pass 1: block argmax — gets A as early as possible
      float Mf = mw;
      int Af = aw;
      dpp_maxcomb<0xB1>(Mf, Af);
      dpp_maxcomb<0x4E>(Mf, Af);
      dpp_maxcomb<0x141>(Mf, Af);
      dpp_maxcomb<0x128>(Mf, Af);
      A = Af;
      // issue next q row NOW (latency hides under the sum pass + next A)
      const uint4* qr = (const uint4*)(qsb + (size_t)A * kE);
      qa = qr[2 * t];
      qb_ = qr[2 * t + 1];
      // pass 2: block denominator
      float sc = sw * __expf(mw - Mf);  // dead waves contribute 0
      sc = dpp_addf<0xB1>(sc);
      sc = dpp_addf<0x4E>(sc);
      sc = dpp_addf<0x141>(sc);
      sc = dpp_addf<0x128>(sc);
      total += -logf(sc);  // chosen logit == M => log_p[act] = -log S
      // next-step jn via locally patched sorted rem:
      // next[j] = old[j] < A ? old[j] : old[j+1]  (shift-left semantics)
      int Rn = R - 1;
#pragma unroll
      for (int r = 0; r < 8; ++r) {
        int j = g + 128 * r;
        jn[r] = (j < Rn) ? ((pra[r] < A) ? pra[r] : prb[r]) : -1;
      }
      // publish shift-remove for future steps (read again only in E',
      // which is fenced by B1'/B2')
      if (tid < R - 1 && myv >= A) rem[tid] = nxt;
    }
    // no end-of-step barrier: rem is next read in phase E' (2 barriers away)
  }
  if (tid == 0) out[b] = total;
}

// ---------------------------------------------------------------------------
extern "C" void kernel_launch(void* const* d_in, const int* in_sizes, int n_in,
                              void* d_out, int out_size, void* d_ws,
                              size_t ws_size, hipStream_t stream) {
  const float* ne = (const float*)d_in[0];
  const float* ge = (const float*)d_in[1];
  const float* Wqkv = (const float*)d_in[2];
  const float* bqkv = (const float*)d_in[3];
  const float* Wfix = (const float*)d_in[4];
  const float* bfix = (const float*)d_in[5];
  const float* Wstep = (const float*)d_in[6];
  const float* bstep = (const float*)d_in[7];
  const float* Wmlp = (const float*)d_in[8];
  const float* bmlp = (const float*)d_in[9];
  float* out = (float*)d_out;

  size_t nkv = (size_t)kB * kN * kE;  // bytes per fp8 tensor
  unsigned char* kq = (unsigned char*)d_ws;
  unsigned char* vq = kq + nkv;
  unsigned char* m2q = vq + nkv;
  __half* qstep = (__half*)(m2q + nkv);     // 2*nkv bytes
  float* qbase = (float*)(qstep + nkv);     // 64 KB
  float* bB = qbase + kB * kE;              // 512 KB
  float* W3 = bB + (size_t)kB * kN;         // 64 KB
  float* b3 = W3 + kE * kE;                 // 512 B
  float* w4 = b3 + kE;                      // 512 B
  float* c4 = w4 + kE;                      // 4 B

  qkv_kernel<<<dim3(kB, (kN + 15) / 16), 256, 0, stream>>>(ne, Wqkv, bqkv, kq,
                                                           vq);
  w3_kernel<<<kE, kE, 0, stream>>>(Wqkv, bqkv, Wmlp, bmlp, W3, b3, w4, c4);
  qbase_kernel<<<kB, kE, 0, stream>>>(ne, ge, Wfix, bfix, Wstep, bstep, qbase);
  qstep_kernel<<<dim3(kB, kN / 8), 128, 0, stream>>>(ne, Wstep, qbase, qstep);
  m2_kernel<<<dim3(kB, kN / 8), 128, 0, stream>>>(ne, W3, b3, w4, c4, m2q, bB);
  rollout_kernel<<<kB, 1024, 0, stream>>>(kq, vq, m2q, qstep, bB, out);
}

// Round 13
// 7207.872 us; speedup vs baseline: 1.6108x; 1.0127x over previous
//
#include <hip/hip_runtime.h>
#include <hip/hip_fp16.h>

constexpr int kB = 128;
constexpr int kN = 1000;
constexpr int kE = 128;
constexpr int kH = 8;
constexpr float kFP8Scale = 64.f;         // fp8 values stored as v*64
constexpr float kQKScale = 0.25f / 64.f;  // 1/sqrt(16) folded with 1/64

typedef _Float16 h2 __attribute__((ext_vector_type(2)));
typedef float f2 __attribute__((ext_vector_type(2)));

__device__ __forceinline__ float fast_tanh(float x) {
  float t = __expf(2.f * x);
  return 1.f - 2.f / (t + 1.f);
}

__device__ __forceinline__ unsigned char enc_fp8(float v) {
  unsigned p = __builtin_amdgcn_cvt_pk_fp8_f32(v, v, 0, false);
  return (unsigned char)(p & 0xFF);
}

// packed fp8-pair dot: sacc += {fp8lo pair}*qa + {fp8hi pair}*qb  (v_pk_fma)
__device__ __forceinline__ void dotp(unsigned u, f2 qa, f2 qb, f2& sacc) {
  f2 lo = __builtin_amdgcn_cvt_pk_f32_fp8(u, false);
  f2 hi = __builtin_amdgcn_cvt_pk_f32_fp8(u, true);
  sacc += lo * qa;
  sacc += hi * qb;
}
// 16-elem fp8 dot (one uint4) against 16 f32 elems in q2[0..7] (f2 pairs).
__device__ __forceinline__ float dot16p(uint4 tq, const f2* q2) {
  f2 s = {0.f, 0.f};
  dotp(tq.x, q2[0], q2[1], s);
  dotp(tq.y, q2[2], q2[3], s);
  dotp(tq.z, q2[4], q2[5], s);
  dotp(tq.w, q2[6], q2[7], s);
  return s.x + s.y;
}
// packed V accumulate: a0 += hv2*{lo pair}; a1 += hv2*{hi pair}
__device__ __forceinline__ void vaccp(unsigned u, f2 hv2, f2& a0, f2& a1) {
  f2 lo = __builtin_amdgcn_cvt_pk_f32_fp8(u, false);
  f2 hi = __builtin_amdgcn_cvt_pk_f32_fp8(u, true);
  a0 += hv2 * lo;
  a1 += hv2 * hi;
}
// unpack 16 f16 (two uint4) -> 8 f2 of f32
__device__ __forceinline__ void unpack16(uint4 a, uint4 b, f2* q2) {
  unsigned w[8] = {a.x, a.y, a.z, a.w, b.x, b.y, b.z, b.w};
#pragma unroll
  for (int i = 0; i < 8; ++i) {
    h2 hh = __builtin_bit_cast(h2, w[i]);
    q2[i] = f2{(float)hh.x, (float)hh.y};
  }
}

// max+argmax combine; tie -> smaller node id (jnp.argmax semantics).
__device__ __forceinline__ void maxcomb(float& m, int& a, float mo, int ao) {
  bool take = (mo > m) || (mo == m && ao < a);
  m = take ? mo : m;
  a = take ? ao : a;
}

// ---- DPP cross-lane helpers (VALU pipe, not DS) ---------------------------
// 0xB1 = quad_perm xor1, 0x4E = quad_perm xor2, 0x141 = row_half_mirror
// (xor4-equiv within octet), 0x128 = row_ror:8 (xor8-equiv within 16 lanes).
template <int CTRL>
__device__ __forceinline__ float dpp_bcastf(float x) {
  return __builtin_bit_cast(
      float, __builtin_amdgcn_update_dpp(0, __builtin_bit_cast(int, x), CTRL,
                                         0xf, 0xf, true));
}
template <int CTRL>
__device__ __forceinline__ int dpp_bcasti(int x) {
  return __builtin_amdgcn_update_dpp(0, x, CTRL, 0xf, 0xf, true);
}
template <int CTRL>
__device__ __forceinline__ float dpp_addf(float x) {
  return x + dpp_bcastf<CTRL>(x);
}
template <int CTRL>
__device__ __forceinline__ void dpp_maxcomb(float& m, int& a) {
  float mo = dpp_bcastf<CTRL>(m);
  int ao = dpp_bcasti<CTRL>(a);
  maxcomb(m, a, mo, ao);
}

// LDS-only barrier: drains DS ops, leaves global register-loads in flight.
__device__ __forceinline__ void barrier_lds() {
  asm volatile("s_waitcnt lgkmcnt(0)" ::: "memory");
  __builtin_amdgcn_s_barrier();
  asm volatile("" ::: "memory");
}

// ---------------------------------------------------------------------------
// Kernel W3 (batch-independent, tiny): W3[gin][i] = sum_g Wlk[gin][g]*Wmlp[i][g]
// b3[i] = sum_g blk[g]*Wmlp[i][g];  w4[gin] = sum_g Wlk[gin][g]*bm[g];
// c4 = sum_g blk[g]*bm[g].   (Wlk = Wqkv[:, 2E:3E], blk = bqkv[2E:3E])
// ---------------------------------------------------------------------------
__global__ __launch_bounds__(128) void w3_kernel(
    const float* __restrict__ Wqkv, const float* __restrict__ bqkv,
    const float* __restrict__ Wmlp, const float* __restrict__ bmlp,
    float* __restrict__ W3, float* __restrict__ b3, float* __restrict__ w4,
    float* __restrict__ c4) {
  __shared__ float lk_s[kE];
  __shared__ float red[kE];
  int gin = blockIdx.x, i = threadIdx.x;
  lk_s[i] = Wqkv[gin * (3 * kE) + 2 * kE + i];
  __syncthreads();
  float s = 0.f;
  for (int g = 0; g < kE; ++g) s += lk_s[g] * Wmlp[i * kE + g];
  W3[gin * kE + i] = s;
  red[i] = lk_s[i] * bmlp[i];
  __syncthreads();
  if (i == 0) {
    float t = 0.f;
    for (int g = 0; g < kE; ++g) t += red[g];
    w4[gin] = t;
  }
  if (gin == 0) {
    float t2 = 0.f;
    for (int g = 0; g < kE; ++g) t2 += bqkv[2 * kE + g] * Wmlp[i * kE + g];
    b3[i] = t2;
    if (i == 0) {
      float t3 = 0.f;
      for (int g = 0; g < kE; ++g) t3 += bqkv[2 * kE + g] * bmlp[g];
      c4[0] = t3;
    }
  }
}

// ---------------------------------------------------------------------------
// Kernel B: qbase[b] = ge@Wfix + bfix + first@Wstep_top + bstep  (fp32)
// ---------------------------------------------------------------------------
__global__ __launch_bounds__(128) void qbase_kernel(
    const float* __restrict__ ne, const float* __restrict__ ge,
    const float* __restrict__ Wfix, const float* __restrict__ bfix,
    const float* __restrict__ Wstep, const float* __restrict__ bstep,
    float* __restrict__ qbase) {
  __shared__ float g[kE], f[kE];
  int b = blockIdx.x, e = threadIdx.x;
  g[e] = ge[b * kE + e];
  f[e] = ne[(size_t)b * kN * kE + e];  // node 0
  __syncthreads();
  float acc = bfix[e] + bstep[e];
  for (int i = 0; i < kE; ++i)
    acc += g[i] * Wfix[i * kE + e] + f[i] * Wstep[i * kE + e];
  qbase[b * kE + e] = acc;
}

// ---------------------------------------------------------------------------
// Kernel N (FUSED per-node projections): one pass over each ne tile produces
//   k / v (fp8*64), M2 = ne@W3+b3 (fp8*64), qstep = (qbase+ne@Wbot)*s (f16),
//   bB = 0.25*(ne·w4 + c4).
// Replaces the former qkv/qstep/m2 kernels (3 launches -> 1; ne tiles read
// once instead of three times).  512 threads: cols 0-255 k/v, 256-383 M2,
// 384-511 qstep; each wave stays within one column class (uniform branch).
// ---------------------------------------------------------------------------
__global__ __launch_bounds__(512) void node_kernel(
    const float* __restrict__ ne, const float* __restrict__ Wqkv,
    const float* __restrict__ bqkv, const float* __restrict__ W3,
    const float* __restrict__ b3, const float* __restrict__ w4,
    const float* __restrict__ c4, const float* __restrict__ Wstep,
    const float* __restrict__ qbase, unsigned char* __restrict__ kq,
    unsigned char* __restrict__ vq, unsigned char* __restrict__ m2q,
    __half* __restrict__ qstep, float* __restrict__ bB) {
  __shared__ float rows[8 * kE];
  __shared__ float w4_s[kE];
  int b = blockIdx.x;
  int n0 = blockIdx.y * 8;  // kN = 1000 = 125 * 8, exact
  int tid = threadIdx.x;

  for (int idx = tid; idx < 8 * kE; idx += 512)
    rows[idx] = ne[((size_t)b * kN + n0) * kE + idx];
  if (tid < kE) w4_s[tid] = w4[tid];
  __syncthreads();

  float acc[8];
#pragma unroll
  for (int r = 0; r < 8; ++r) acc[r] = 0.f;

  int j = tid;
  if (j < 256) {  // k / v columns (Wqkv cols 0..255)
    for (int i = 0; i < kE; ++i) {
      float w = Wqkv[i * (3 * kE) + j];
#pragma unroll
      for (int r = 0; r < 8; ++r) acc[r] += rows[r * kE + i] * w;
    }
    float bias = bqkv[j];
    unsigned char* dst = (j < kE) ? kq : vq;
    int col = j & 127;
    for (int r = 0; r < 8; ++r)
      dst[(size_t)(b * kN + n0 + r) * kE + col] =
          enc_fp8((acc[r] + bias) * kFP8Scale);
  } else if (j < 384) {  // M2 columns
    int col = j - 256;
    for (int i = 0; i < kE; ++i) {
      float w = W3[i * kE + col];
#pragma unroll
      for (int r = 0; r < 8; ++r) acc[r] += rows[r * kE + i] * w;
    }
    float bias = b3[col];
    for (int r = 0; r < 8; ++r)
      m2q[(size_t)(b * kN + n0 + r) * kE + col] =
          enc_fp8((acc[r] + bias) * kFP8Scale);
  } else {  // qstep columns
    int col = j - 384;
    const float* Wbot = Wstep + kE * kE;
    for (int i = 0; i < kE; ++i) {
      float w = Wbot[i * kE + col];
#pragma unroll
      for (int r = 0; r < 8; ++r) acc[r] += rows[r * kE + i] * w;
    }
    float qb = qbase[b * kE + col];
    for (int r = 0; r < 8; ++r)
      qstep[((size_t)b * kN + n0 + r) * kE + col] =
          __float2half((qb + acc[r]) * kQKScale);
  }
  if (tid < 8) {  // pre-scaled logit bias per node row
    float s = c4[0];
    for (int g = 0; g < kE; ++g) s += rows[tid * kE + g] * w4_s[g];
    bB[b * kN + n0 + tid] = 0.25f * s;
  }
}

// ---------------------------------------------------------------------------
// Kernel C: 999-step rollout, one 1024-thread block per batch element.
// BYTE-IDENTICAL to round 12 (6.89 ms verified): fused scores+ctx phase A,
// M2-folded logits (no x matvec), 3 barriers/step, register jn maintenance,
// two-pass max-then-sum reductions, argmax-first F with early q issue.
// ---------------------------------------------------------------------------
__global__ __launch_bounds__(1024) void rollout_kernel(
    const unsigned char* __restrict__ kq, const unsigned char* __restrict__ vq,
    const unsigned char* __restrict__ m2q, const __half* __restrict__ qstep,
    const float* __restrict__ bB, float* __restrict__ out) {
  __shared__ __align__(16) int rem[1024];       // SORTED live ids (padded)
  __shared__ __align__(16) float parts[kE][65]; // ctx chunk partials, 33 KB
  __shared__ __align__(16) float bb_s[1024];    // 0.25*(bm·LK_j), 4 KB
  __shared__ __align__(16) float ctx[kE];
  __shared__ float redSum[16][kH];
  __shared__ __align__(16) float4 redPack[16];  // (m, ssum, argbits, -)

  int b = blockIdx.x;
  int tid = threadIdx.x;
  int lane = tid & 63;
  int wave = tid >> 6;
  int g = tid >> 3;  // node-group 0..127; slots j = g + 128r
  int t = tid & 7;   // head / uint4 chunk within row

  const unsigned char* kqb = kq + (size_t)b * kN * kE;
  const unsigned char* vqb = vq + (size_t)b * kN * kE;
  const unsigned char* mqb = m2q + (size_t)b * kN * kE;
  const __half* qsb = qstep + (size_t)b * kN * kE;

  // stage per-batch logit biases (read once per step per thread)
  if (tid < kN) bb_s[tid] = bB[(size_t)b * kN + tid];
  // init sorted live list (padded with valid ids for safe speculative reads)
  rem[tid] = (tid < kN - 1) ? tid + 1 : kN - 1;

  // current action + its q row (prefetched into registers; node 0 first)
  int A = 0;
  uint4 qa, qb_;
  {
    const uint4* qr = (const uint4*)qsb;
    qa = qr[2 * t];
    qb_ = qr[2 * t + 1];
  }
  float total = 0.f;

  // step-0 jn (initial rem[j] = j+1), register resident
  int jn[8];
#pragma unroll
  for (int r = 0; r < 8; ++r) {
    int j = g + 128 * r;
    jn[r] = (j < kN - 1) ? j + 1 : -1;
  }

  barrier_lds();  // init visible

  for (int step = 0; step < kN - 1; ++step) {
    int R = kN - 1 - step;  // live count (deterministic)

    // ========== phase A: fused scores + ctx accumulation =================
    // K/V loads issue immediately (jn is register-resident, no rem reads)
    uint4 kb0, vb0, kb1, vb1;
    if (jn[0] >= 0) {
      kb0 = ((const uint4*)(kqb + (size_t)jn[0] * kE))[t];
      vb0 = ((const uint4*)(vqb + (size_t)jn[0] * kE))[t];
    }
    if (jn[1] >= 0) {
      kb1 = ((const uint4*)(kqb + (size_t)jn[1] * kE))[t];
      vb1 = ((const uint4*)(vqb + (size_t)jn[1] * kE))[t];
    }
    f2 q2[8];
    unpack16(qa, qb_, q2);  // 16 cvt, once per step
    f2 acc2[8];             // ctx accum as f32 pairs (elems 4c..4c+3 per c)
#pragma unroll
    for (int i = 0; i < 8; ++i) acc2[i] = f2{0.f, 0.f};
    float den = 0.f;
#pragma unroll
    for (int r = 0; r < 8; ++r) {
      if (jn[r] < 0) break;  // sorted rem: deadness is monotone in r
      uint4 kk = (r & 1) ? kb1 : kb0;
      uint4 vv = (r & 1) ? vb1 : vb0;
      if (r + 2 < 8 && jn[r + 2] >= 0) {  // depth-2 slot pipeline
        if (r & 1) {
          kb1 = ((const uint4*)(kqb + (size_t)jn[r + 2] * kE))[t];
          vb1 = ((const uint4*)(vqb + (size_t)jn[r + 2] * kE))[t];
        } else {
          kb0 = ((const uint4*)(kqb + (size_t)jn[r + 2] * kE))[t];
          vb0 = ((const uint4*)(vqb + (size_t)jn[r + 2] * kE))[t];
        }
      }
      float s = dot16p(kk, q2);
      float hv = __expf(s);  // full head-t score (d=16): scores tiny
      den += hv;
      f2 hv2 = {hv, hv};
      vaccp(vv.x, hv2, acc2[0], acc2[1]);
      vaccp(vv.y, hv2, acc2[2], acc2[3]);
      vaccp(vv.z, hv2, acc2[4], acc2[5]);
      vaccp(vv.w, hv2, acc2[6], acc2[7]);
    }
    // M2 row prefetch (cover: rest of A + B1 + C; consumed in E)
    uint4 mu[8];
#pragma unroll
    for (int r = 0; r < 8; ++r)
      if (jn[r] >= 0) mu[r] = ((const uint4*)(mqb + (size_t)jn[r] * kE))[t];
    // den: reduce over the 8 g-groups of this wave (preserve t = lane%8)
    den = dpp_addf<0x128>(den);
    den += __shfl_xor(den, 16);
    den += __shfl_xor(den, 32);
    if (lane < kH) redSum[wave][lane] = den;  // lane==t for lanes 0..7
    // acc: unpack to scalars, gw-pair fold (VALU), write 64-chunk parts
    {
      float av[16];
#pragma unroll
      for (int c = 0; c < 4; ++c) {
        av[4 * c + 0] = acc2[2 * c].x;
        av[4 * c + 1] = acc2[2 * c].y;
        av[4 * c + 2] = acc2[2 * c + 1].x;
        av[4 * c + 3] = acc2[2 * c + 1].y;
      }
#pragma unroll
      for (int i = 0; i < 16; ++i) av[i] = dpp_addf<0x128>(av[i]);
      if (((lane >> 3) & 1) == 0) {
        int chunk = wave * 4 + (lane >> 4);  // 0..63
#pragma unroll
        for (int i = 0; i < 16; ++i)
          parts[t * 16 + i][(chunk + 4 * t) & 63] = av[i];  // bank-injective
      }
    }
    barrier_lds();  // B1: parts, redSum ready

    // ========== phase C: finalize ctx (all threads, DPP octet tree) ======
    {
      int e = tid >> 3, k = tid & 7, hh = e >> 4;
      float s = 0.f;
#pragma unroll
      for (int m = 0; m < 8; ++m)
        s += parts[e][((8 * k + m) + 4 * hh) & 63];
      float d = redSum[2 * k][hh] + redSum[2 * k + 1][hh];
      s = dpp_addf<0xB1>(s);
      s = dpp_addf<0x4E>(s);
      s = dpp_addf<0x141>(s);
      d = dpp_addf<0xB1>(d);
      d = dpp_addf<0x4E>(d);
      d = dpp_addf<0x141>(d);
      if (k == 0) ctx[e] = s / (d * kFP8Scale);
    }
    barrier_lds();  // B2: ctx ready

    // ========== phase E: logits via M2 (mu in registers) + rem pre-reads =
    // rem reads for shift-remove AND next-step jn patch happen HERE
    // (pre-B3); B3 fences them from the phase-F writes.
    int myv = rem[tid];
    int nxt = rem[(tid < 1023) ? tid + 1 : 1023];
    int pra[8], prb[8];
#pragma unroll
    for (int r = 0; r < 8; ++r) {
      int j = g + 128 * r;  // <= 1023
      pra[r] = rem[j];
      prb[r] = rem[(j < 1023) ? j + 1 : 1023];
    }
    float m0raw = 0.f;
    int arg = 0x7fffffff;
    {
      f2 c2[8];
      const float4* cc = (const float4*)(ctx + t * 16);
#pragma unroll
      for (int k4 = 0; k4 < 4; ++k4) {
        float4 cv = cc[k4];
        c2[2 * k4] = f2{cv.x, cv.y};
        c2[2 * k4 + 1] = f2{cv.z, cv.w};
      }
#pragma unroll
      for (int r = 0; r < 8; ++r)
        if (jn[r] >= 0) {  // uniform within each octet (depends on g only)
          float s = dot16p(mu[r], c2);
          s = dpp_addf<0xB1>(s);
          s = dpp_addf<0x4E>(s);
          s = dpp_addf<0x141>(s);
          if (t == r) {  // lane t captures entry r (raw dot)
            m0raw = s;
            arg = jn[r];
          }
        }
    }
    // bias + tanh once per thread (its captured entry), then two-pass
    // wave reduction: max+arg butterfly, then one exp + add butterfly.
    float m0 = -1e30f;
    if (arg != 0x7fffffff)
      m0 = fast_tanh(kQKScale * m0raw + bb_s[arg]) * 10.f;
    float M = m0;
    int argM = arg;
    dpp_maxcomb<0xB1>(M, argM);
    dpp_maxcomb<0x4E>(M, argM);
    dpp_maxcomb<0x141>(M, argM);
    dpp_maxcomb<0x128>(M, argM);
#pragma unroll
    for (int off = 16; off <= 32; off <<= 1) {
      float mo = __shfl_xor(M, off);
      int ao = __shfl_xor(argM, off);
      maxcomb(M, argM, mo, ao);
    }
    float ex = __expf(m0 - M);  // dead lanes: exp(-huge) = 0
    ex = dpp_addf<0xB1>(ex);
    ex = dpp_addf<0x4E>(ex);
    ex = dpp_addf<0x141>(ex);
    ex = dpp_addf<0x128>(ex);
    ex += __shfl_xor(ex, 16);
    ex += __shfl_xor(ex, 32);
    if (lane == 0)
      redPack[wave] = make_float4(M, ex, __int_as_float(argM), 0.f);
    barrier_lds();  // B3: reductions ready; rem reads fenced from writes

    // ====== phase F: argmax FIRST (q issues early), then denominator =====
    {
      float4 rp = redPack[lane & 15];
      float mw = rp.x, sw = rp.y;
      int aw = __float_as_int(rp.z);
      // pass 1: block argmax — gets A as early as possible
      float Mf = mw;
      int Af = aw;
      dpp_maxcomb<0xB1>(Mf, Af);
      dpp_maxcomb<0x4E>(Mf, Af);
      dpp_maxcomb<0x141>(Mf, Af);
      dpp_maxcomb<0x128>(Mf, Af);
      A = Af;
      // issue next q row NOW (latency hides under the sum pass + next A)
      const uint4* qr = (const uint4*)(qsb + (size_t)A * kE);
      qa = qr[2 * t];
      qb_ = qr[2 * t + 1];
      // pass 2: block denominator
      float sc = sw * __expf(mw - Mf);  // dead waves contribute 0
      sc = dpp_addf<0xB1>(sc);
      sc = dpp_addf<0x4E>(sc);
      sc = dpp_addf<0x141>(sc);
      sc = dpp_addf<0x128>(sc);
      total += -logf(sc);  // chosen logit == M => log_p[act] = -log S
      // next-step jn via locally patched sorted rem:
      // next[j] = old[j] < A ? old[j] : old[j+1]  (shift-left semantics)
      int Rn = R - 1;
#pragma unroll
      for (int r = 0; r < 8; ++r) {
        int j = g + 128 * r;
        jn[r] = (j < Rn) ? ((pra[r] < A) ? pra[r] : prb[r]) : -1;
      }
      // publish shift-remove for future steps (read again only in E',
      // which is fenced by B1'/B2')
      if (tid < R - 1 && myv >= A) rem[tid] = nxt;
    }
    // no end-of-step barrier: rem is next read in phase E' (2 barriers away)
  }
  if (tid == 0) out[b] = total;
}

// ---------------------------------------------------------------------------
extern "C" void kernel_launch(void* const* d_in, const int* in_sizes, int n_in,
                              void* d_out, int out_size, void* d_ws,
                              size_t ws_size, hipStream_t stream) {
  const float* ne = (const float*)d_in[0];
  const float* ge = (const float*)d_in[1];
  const float* Wqkv = (const float*)d_in[2];
  const float* bqkv = (const float*)d_in[3];
  const float* Wfix = (const float*)d_in[4];
  const float* bfix = (const float*)d_in[5];
  const float* Wstep = (const float*)d_in[6];
  const float* bstep = (const float*)d_in[7];
  const float* Wmlp = (const float*)d_in[8];
  const float* bmlp = (const float*)d_in[9];
  float* out = (float*)d_out;

  size_t nkv = (size_t)kB * kN * kE;  // bytes per fp8 tensor
  unsigned char* kq = (unsigned char*)d_ws;
  unsigned char* vq = kq + nkv;
  unsigned char* m2q = vq + nkv;
  __half* qstep = (__half*)(m2q + nkv);     // 2*nkv bytes
  float* qbase = (float*)(qstep + nkv);     // 64 KB
  float* bB = qbase + kB * kE;              // 512 KB
  float* W3 = bB + (size_t)kB * kN;         // 64 KB
  float* b3 = W3 + kE * kE;                 // 512 B
  float* w4 = b3 + kE;                      // 512 B
  float* c4 = w4 + kE;                      // 4 B

  qbase_kernel<<<kB, kE, 0, stream>>>(ne, ge, Wfix, bfix, Wstep, bstep, qbase);
  w3_kernel<<<kE, kE, 0, stream>>>(Wqkv, bqkv, Wmlp, bmlp, W3, b3, w4, c4);
  node_kernel<<<dim3(kB, kN / 8), 512, 0, stream>>>(
      ne, Wqkv, bqkv, W3, b3, w4, c4, Wstep, qbase, kq, vq, m2q, qstep, bB);
  rollout_kernel<<<kB, 1024, 0, stream>>>(kq, vq, m2q, qstep, bB, out);
}